// Round 1
// baseline (230.120 us; speedup 1.0000x reference)
//
#include <hip/hip_runtime.h>
#include <math.h>

#define MM 4096
#define DD 2048

// ws layout (floats):
// [0..M)     qt
// [M..2M)    k   (already scaled by 1/sqrt(M))
// [2M..3M)   v
// [3M+0] it, [3M+1] ft, [3M+2] ot, [3M+3] denom

// ---------------- Kernel A: qt / k / v GEMVs (one wave per row) ----------------
__global__ __launch_bounds__(256) void gemv3_kernel(
    const float* __restrict__ Wq, const float* __restrict__ bq,
    const float* __restrict__ Wk, const float* __restrict__ bk,
    const float* __restrict__ Wv, const float* __restrict__ bV,
    const float* __restrict__ x, float* __restrict__ ws)
{
    int wave  = (blockIdx.x * blockDim.x + threadIdx.x) >> 6;  // 0 .. 3*M-1
    int lane  = threadIdx.x & 63;
    int which = wave >> 12;        // /M : 0=q, 1=k, 2=v
    int row   = wave & (MM - 1);   // %M
    const float* W = (which == 0) ? Wq : ((which == 1) ? Wk : Wv);
    const float* b = (which == 0) ? bq : ((which == 1) ? bk : bV);
    const float4* wrow = (const float4*)(W + (size_t)row * DD);
    const float4* xv   = (const float4*)x;
    float acc = 0.f;
    #pragma unroll
    for (int t = 0; t < DD / 4 / 64; ++t) {   // 8 iters
        float4 w  = wrow[lane + 64 * t];
        float4 xx = xv  [lane + 64 * t];
        acc += w.x * xx.x + w.y * xx.y + w.z * xx.z + w.w * xx.w;
    }
    for (int off = 32; off; off >>= 1) acc += __shfl_down(acc, off, 64);
    if (lane == 0) {
        float r = acc + b[row];
        if (which == 1) r *= (1.0f / 64.0f);   // 1/sqrt(4096)
        ws[which * MM + row] = r;
    }
}

// ---------------- Kernel B: it / ft / ot scalars (double accumulation) ----------------
__global__ __launch_bounds__(256) void scalars_kernel(
    const float* __restrict__ Wi, const float* __restrict__ bi,
    const float* __restrict__ Wf, const float* __restrict__ bf,
    const float* __restrict__ Wo, const float* __restrict__ bo,
    const float* __restrict__ x, float* __restrict__ ws)
{
    __shared__ double sred[3][4];
    double a0 = 0, a1 = 0, a2 = 0;
    const float4* xv  = (const float4*)x;
    const float4* wiv = (const float4*)Wi;
    const float4* wfv = (const float4*)Wf;
    const float4* wov = (const float4*)Wo;
    for (int t = threadIdx.x; t < DD / 4; t += 256) {
        float4 xx = xv[t];
        float4 wi4 = wiv[t];
        a0 += (double)wi4.x * xx.x + (double)wi4.y * xx.y + (double)wi4.z * xx.z + (double)wi4.w * xx.w;
        float4 wf4 = wfv[t];
        a1 += (double)wf4.x * xx.x + (double)wf4.y * xx.y + (double)wf4.z * xx.z + (double)wf4.w * xx.w;
        float4 wo4 = wov[t];
        a2 += (double)wo4.x * xx.x + (double)wo4.y * xx.y + (double)wo4.z * xx.z + (double)wo4.w * xx.w;
    }
    int lane = threadIdx.x & 63, wid = threadIdx.x >> 6;
    for (int off = 32; off; off >>= 1) {
        a0 += __shfl_down(a0, off, 64);
        a1 += __shfl_down(a1, off, 64);
        a2 += __shfl_down(a2, off, 64);
    }
    if (lane == 0) { sred[0][wid] = a0; sred[1][wid] = a1; sred[2][wid] = a2; }
    __syncthreads();
    if (threadIdx.x == 0) {
        double s0 = 0, s1 = 0, s2 = 0;
        for (int w = 0; w < 4; ++w) { s0 += sred[0][w]; s1 += sred[1][w]; s2 += sred[2][w]; }
        ws[3 * MM + 0] = (float)exp(s0 + (double)bi[0]);
        ws[3 * MM + 1] = (float)exp(s1 + (double)bf[0]);
        ws[3 * MM + 2] = (float)(1.0 / (1.0 + exp(-(s2 + (double)bo[0]))));
    }
}

// ---------------- Kernel C: n and denom ----------------
__global__ __launch_bounds__(1024) void n_denom_kernel(
    const float* __restrict__ n_prev, float* __restrict__ ws, float* __restrict__ n_out)
{
    __shared__ float sred[16];
    float it = ws[3 * MM + 0], ft = ws[3 * MM + 1];
    float acc = 0.f;
    for (int i = threadIdx.x; i < MM; i += 1024) {
        float ni = fmaf(ft, n_prev[i], it * ws[MM + i]);  // ft*n_prev + it*k
        n_out[i] = ni;
        acc = fmaf(ni, ws[i], acc);                       // n . qt
    }
    int lane = threadIdx.x & 63, wid = threadIdx.x >> 6;
    for (int off = 32; off; off >>= 1) acc += __shfl_down(acc, off, 64);
    if (lane == 0) sred[wid] = acc;
    __syncthreads();
    if (threadIdx.x == 0) {
        float s = 0.f;
        for (int w = 0; w < 16; ++w) s += sred[w];
        ws[3 * MM + 3] = fmaxf(fabsf(s), 1.0f);
    }
}

// ---------------- Kernel D: C = ft*cp + it*outer(v,k), fused h = C@qt ----------------
__global__ __launch_bounds__(256) void rowC_kernel(
    const float* __restrict__ cp, const float* __restrict__ ws,
    float* __restrict__ C_out, float* __restrict__ ht_out)
{
    __shared__ float sred[4];
    int row = blockIdx.x;
    float it = ws[3 * MM + 0], ft = ws[3 * MM + 1];
    float ot = ws[3 * MM + 2], denom = ws[3 * MM + 3];
    float ivi = it * ws[2 * MM + row];   // it * v[row]
    const float4* cprow = (const float4*)(cp + (size_t)row * MM);
    float4*       crow  = (float4*)(C_out + (size_t)row * MM);
    const float4* kv = (const float4*)(ws + MM);
    const float4* qv = (const float4*)ws;
    float acc = 0.f;
    #pragma unroll 4
    for (int t = threadIdx.x; t < MM / 4; t += 256) {
        float4 c = cprow[t], kk = kv[t], qq = qv[t];
        float4 o;
        o.x = fmaf(ivi, kk.x, ft * c.x);
        o.y = fmaf(ivi, kk.y, ft * c.y);
        o.z = fmaf(ivi, kk.z, ft * c.z);
        o.w = fmaf(ivi, kk.w, ft * c.w);
        crow[t] = o;
        acc += o.x * qq.x + o.y * qq.y + o.z * qq.z + o.w * qq.w;
    }
    int lane = threadIdx.x & 63, wid = threadIdx.x >> 6;
    for (int off = 32; off; off >>= 1) acc += __shfl_down(acc, off, 64);
    if (lane == 0) sred[wid] = acc;
    __syncthreads();
    if (threadIdx.x == 0) {
        float s = sred[0] + sred[1] + sred[2] + sred[3];
        ht_out[row] = ot * (s / denom);
    }
}

extern "C" void kernel_launch(void* const* d_in, const int* in_sizes, int n_in,
                              void* d_out, int out_size, void* d_ws, size_t ws_size,
                              hipStream_t stream)
{
    const float* x      = (const float*)d_in[0];
    const float* cp     = (const float*)d_in[1];
    const float* n_prev = (const float*)d_in[2];
    const float* Wq = (const float*)d_in[3];
    const float* bq = (const float*)d_in[4];
    const float* Wk = (const float*)d_in[5];
    const float* bk = (const float*)d_in[6];
    const float* Wv = (const float*)d_in[7];
    const float* bV = (const float*)d_in[8];
    const float* Wi = (const float*)d_in[9];
    const float* bi = (const float*)d_in[10];
    const float* Wf = (const float*)d_in[11];
    const float* bf = (const float*)d_in[12];
    const float* Wo = (const float*)d_in[13];
    const float* bo = (const float*)d_in[14];

    float* out = (float*)d_out;
    float* ht  = out;                       // (M,1)
    float* C   = out + MM;                  // (M,M)
    float* n   = out + MM + (size_t)MM * MM;// (M,1)
    float* ws  = (float*)d_ws;

    gemv3_kernel  <<<3 * MM / 4, 256, 0, stream>>>(Wq, bq, Wk, bk, Wv, bV, x, ws);
    scalars_kernel<<<1, 256, 0, stream>>>(Wi, bi, Wf, bf, Wo, bo, x, ws);
    n_denom_kernel<<<1, 1024, 0, stream>>>(n_prev, ws, n);
    rowC_kernel   <<<MM, 256, 0, stream>>>(cp, ws, C, ht);
}